// Round 9
// baseline (308.027 us; speedup 1.0000x reference)
//
#include <hip/hip_runtime.h>
#include <hip/hip_bf16.h>
#include <cstdint>

#define N_SRC 100000
#define N_DST 25000
#define N_EDGE 300000
// D_IN = D_HID = D_OUT = 256, concat K = 512

typedef float f32x4 __attribute__((ext_vector_type(4)));
typedef __bf16 bf16x8 __attribute__((ext_vector_type(8)));

__device__ __forceinline__ unsigned short f2bf(float f) {
    union { float f; unsigned int u; } v; v.f = f;
    unsigned int u = v.u;
    u += 0x7FFFu + ((u >> 16) & 1u);   // RNE; inputs finite
    return (unsigned short)(u >> 16);
}
__device__ __forceinline__ float bf2f(unsigned int bits16) {
    union { unsigned int u; float f; } v; v.u = bits16 << 16;
    return v.f;
}

// asm-pinned 16B loads (cannot be sunk/reordered vs the counted waits)
__device__ __forceinline__ void gload16(uint4& d, const void* p) {
    asm volatile("global_load_dwordx4 %0, %1, off" : "=v"(d) : "v"(p) : "memory");
}
__device__ __forceinline__ void gload16(float4& d, const void* p) {
    asm volatile("global_load_dwordx4 %0, %1, off" : "=v"(d) : "v"(p) : "memory");
}
#define VMWAIT(N) do { asm volatile("s_waitcnt vmcnt(" #N ")" ::: "memory"); \
                       __builtin_amdgcn_sched_barrier(0); } while (0)

// ---- cast + transpose weights: Qt[n][k] = bf16(Q_w[k][n]), Wt[n][k] = bf16(W_w[k][n])
__global__ void cast_weights(const float* __restrict__ Qw, const float* __restrict__ Ww,
                             unsigned short* __restrict__ Qt, unsigned short* __restrict__ Wt) {
    int i = blockIdx.x * blockDim.x + threadIdx.x;
    if (i < 256 * 256) {
        int n = i >> 8, k = i & 255;
        Qt[n * 256 + k] = f2bf(Qw[k * 256 + n]);
    } else if (i < 256 * 256 + 512 * 256) {
        int j = i - 256 * 256;
        int n = j >> 9, k = j & 511;
        Wt[n * 512 + k] = f2bf(Ww[k * 256 + n]);
    }
}

// ---- CSR build
__global__ void hist_kernel(const int* __restrict__ dst_idx, int* __restrict__ counts) {
    int i = blockIdx.x * blockDim.x + threadIdx.x;
    if (i < N_EDGE) atomicAdd(&counts[dst_idx[i]], 1);
}

__global__ __launch_bounds__(1024) void scan_kernel(const int* __restrict__ counts,
                                                    int* __restrict__ offsets, int n) {
    __shared__ int wsum[16];
    const int t = threadIdx.x;
    const int wid = t >> 6, lane = t & 63;
    int carry = 0;
    if (t == 0) offsets[0] = 0;
    for (int base = 0; base < n; base += 1024) {
        int x = (base + t < n) ? counts[base + t] : 0;
        #pragma unroll
        for (int off = 1; off < 64; off <<= 1) {
            int y = __shfl_up(x, off, 64);
            if (lane >= off) x += y;
        }
        if (lane == 63) wsum[wid] = x;
        __syncthreads();
        if (t < 16) {
            int w = wsum[t];
            #pragma unroll
            for (int off = 1; off < 16; off <<= 1) {
                int y = __shfl_up(w, off, 64);
                if (t >= off) w += y;
            }
            wsum[t] = w;
        }
        __syncthreads();
        int pre = (wid > 0) ? wsum[wid - 1] : 0;
        int incl = carry + pre + x;
        if (base + t < n) offsets[base + t + 1] = incl;
        carry += wsum[15];
        __syncthreads();
    }
}

__global__ void scatter_kernel(const int* __restrict__ dst_idx, const int* __restrict__ offsets,
                               int* __restrict__ counts, int* __restrict__ edge_list) {
    int i = blockIdx.x * blockDim.x + threadIdx.x;
    if (i < N_EDGE) {
        int d = dst_idx[i];
        int pos = offsets[d] + (atomicSub(&counts[d], 1) - 1);
        edge_list[pos] = i;
    }
}

// ---- GEMM1 stream: nft = relu(h_src @ Qt^T + Qb), bf16 out.
// Wave-independent 32(M)x32(N) tiles; B panel (32 cols x 256 K) held in regs
// (16 uint4, loaded once from L2-hot Qt); A (f32) streams via asm-pinned
// 3-slot ring (4 loads/slot), counted vmcnt. Zero LDS, zero barriers.
// 3125 row-tiles x 8 col-panels = 25000 waves; 12 waves/CU of pure TLP.
__global__ __launch_bounds__(256) void gemm1_stream(
    const float* __restrict__ Af, const unsigned short* __restrict__ Bt,
    const float* __restrict__ bias, unsigned short* __restrict__ Cb)
{
    const int wid = blockIdx.x * 4 + (threadIdx.x >> 6);
    const int mt = wid >> 3, nt = wid & 7;
    const int lane = threadIdx.x & 63, g = lane >> 4, cl = lane & 15;
    const int m0 = mt * 32, n0 = nt * 32;

    f32x4 acc[2][2];
    #pragma unroll
    for (int i = 0; i < 2; ++i)
        #pragma unroll
        for (int j = 0; j < 2; ++j)
            acc[i][j] = (f32x4){0.f, 0.f, 0.f, 0.f};

    uint4 Br[2][8];                 // full B panel: 2 ni x 8 k-slices
    #pragma unroll
    for (int kf = 0; kf < 8; ++kf)
        #pragma unroll
        for (int ni = 0; ni < 2; ++ni)
            gload16(Br[ni][kf], Bt + (size_t)(n0 + ni * 16 + cl) * 256 + kf * 32 + g * 8);

    const float* a0 = Af + (size_t)(m0 + cl) * 256;
    const float* a1 = Af + (size_t)(m0 + 16 + cl) * 256;
    float4 Ar[3][2][2];             // [slot][mi][half]
    auto issueA = [&](int slot, int ks) {
        const float* p0 = a0 + ks * 32 + g * 8;
        const float* p1 = a1 + ks * 32 + g * 8;
        gload16(Ar[slot][0][0], p0); gload16(Ar[slot][0][1], p0 + 4);
        gload16(Ar[slot][1][0], p1); gload16(Ar[slot][1][1], p1 + 4);
    };
    auto compute = [&](int slot, int ks) {
        #pragma unroll
        for (int mi = 0; mi < 2; ++mi) {
            const float4 lo = Ar[slot][mi][0], hi = Ar[slot][mi][1];
            bf16x8 af;
            af[0] = (__bf16)lo.x; af[1] = (__bf16)lo.y; af[2] = (__bf16)lo.z; af[3] = (__bf16)lo.w;
            af[4] = (__bf16)hi.x; af[5] = (__bf16)hi.y; af[6] = (__bf16)hi.z; af[7] = (__bf16)hi.w;
            #pragma unroll
            for (int ni = 0; ni < 2; ++ni)
                acc[mi][ni] = __builtin_amdgcn_mfma_f32_16x16x32_bf16(
                    af, __builtin_bit_cast(bf16x8, Br[ni][ks]), acc[mi][ni], 0, 0, 0);
        }
    };

    issueA(0, 0); issueA(1, 1); issueA(2, 2);    // 16 B + 12 A outstanding
    VMWAIT(8); compute(0, 0); issueA(0, 3);
    VMWAIT(8); compute(1, 1); issueA(1, 4);
    VMWAIT(8); compute(2, 2); issueA(2, 5);
    VMWAIT(8); compute(0, 3); issueA(0, 6);
    VMWAIT(8); compute(1, 4); issueA(1, 7);
    VMWAIT(8); compute(2, 5);
    VMWAIT(4); compute(0, 6);
    VMWAIT(0); compute(1, 7);

    float bcol[2];
    #pragma unroll
    for (int ni = 0; ni < 2; ++ni) bcol[ni] = bias[n0 + ni * 16 + cl];
    #pragma unroll
    for (int mi = 0; mi < 2; ++mi) {
        const int rowb = m0 + mi * 16 + g * 4;
        #pragma unroll
        for (int ni = 0; ni < 2; ++ni) {
            const int col = n0 + ni * 16 + cl;
            #pragma unroll
            for (int r = 0; r < 4; ++r) {
                float v = fmaxf(acc[mi][ni][r] + bcol[ni], 0.f);
                Cb[(size_t)(rowb + r) * 256 + col] = f2bf(v);   // 3125*32 = N_SRC exact
            }
        }
    }
}

// ---- GEMM2 stream: out = rownorm(relu(xb @ Wt^T + Wb)), f32 out.
// Same wave pattern (32x32 tiles, K=512 -> 16 ks); B panel in regs in two
// half-K phases (16 uint4 each, reloaded after phase-0 consumed). Block =
// 512 thr = 8 waves covering all 8 col panels of one 32-row tile; LDS only
// for the epilogue row-norm exchange.
__global__ __launch_bounds__(512) void gemm2_stream(
    const unsigned short* __restrict__ Ab, const unsigned short* __restrict__ Bt,
    const float* __restrict__ bias, float* __restrict__ Cf, int M)
{
    __shared__ float norml[8][32];
    const int tid = threadIdx.x;
    const int wv = tid >> 6, lane = tid & 63, g = lane >> 4, cl = lane & 15;
    const int m0 = blockIdx.x * 32, n0 = wv * 32;
    const int r0 = min(m0 + cl, M - 1);
    const int r1 = min(m0 + 16 + cl, M - 1);
    const unsigned short* a0 = Ab + (size_t)r0 * 512;
    const unsigned short* a1 = Ab + (size_t)r1 * 512;

    f32x4 acc[2][2];
    #pragma unroll
    for (int i = 0; i < 2; ++i)
        #pragma unroll
        for (int j = 0; j < 2; ++j)
            acc[i][j] = (f32x4){0.f, 0.f, 0.f, 0.f};

    uint4 Br[2][8];                 // half-K B panel (phase p: kf 8p..8p+7)
    auto issueB = [&](int p) {
        #pragma unroll
        for (int kf = 0; kf < 8; ++kf)
            #pragma unroll
            for (int ni = 0; ni < 2; ++ni)
                gload16(Br[ni][kf],
                        Bt + (size_t)(n0 + ni * 16 + cl) * 512 + (p * 8 + kf) * 32 + g * 8);
    };
    uint4 Ar[3][2];                 // [slot][mi]
    auto issueA = [&](int slot, int ks) {
        gload16(Ar[slot][0], a0 + ks * 32 + g * 8);
        gload16(Ar[slot][1], a1 + ks * 32 + g * 8);
    };
    auto compute = [&](int slot, int ks) {
        #pragma unroll
        for (int mi = 0; mi < 2; ++mi) {
            const bf16x8 af = __builtin_bit_cast(bf16x8, Ar[slot][mi]);
            #pragma unroll
            for (int ni = 0; ni < 2; ++ni)
                acc[mi][ni] = __builtin_amdgcn_mfma_f32_16x16x32_bf16(
                    af, __builtin_bit_cast(bf16x8, Br[ni][ks & 7]), acc[mi][ni], 0, 0, 0);
        }
    };

    issueB(0);                              // 16
    issueA(0, 0); issueA(1, 1); issueA(2, 2);   // +6 = 22
    VMWAIT(4); compute(0, 0); issueA(0, 3);
    VMWAIT(4); compute(1, 1); issueA(1, 4);
    VMWAIT(4); compute(2, 2); issueA(2, 5);
    VMWAIT(4); compute(0, 3); issueA(0, 6);
    VMWAIT(4); compute(1, 4); issueA(1, 7);
    VMWAIT(4); compute(2, 5); issueA(2, 8);
    VMWAIT(4); compute(0, 6); issueA(0, 9);
    VMWAIT(4); compute(1, 7); issueB(1); issueA(1, 10);   // phase-0 B fully consumed
    VMWAIT(2); compute(2, 8); issueA(2, 11);              // drains A8,A9,B1
    VMWAIT(2); compute(0, 9); issueA(0, 12);
    VMWAIT(2); compute(1, 10); issueA(1, 13);
    VMWAIT(2); compute(2, 11); issueA(2, 14);
    VMWAIT(2); compute(0, 12); issueA(0, 15);
    VMWAIT(2); compute(1, 13);
    VMWAIT(2); compute(2, 14);
    VMWAIT(0); compute(0, 15);

    float bcol[2];
    #pragma unroll
    for (int ni = 0; ni < 2; ++ni) bcol[ni] = bias[n0 + ni * 16 + cl];

    float keep[2][2][4];
    #pragma unroll
    for (int mi = 0; mi < 2; ++mi) {
        #pragma unroll
        for (int r = 0; r < 4; ++r) {
            float s = 0.f;
            #pragma unroll
            for (int ni = 0; ni < 2; ++ni) {
                float v = fmaxf(acc[mi][ni][r] + bcol[ni], 0.f);
                keep[mi][ni][r] = v;
                s += v * v;
            }
            #pragma unroll
            for (int m = 1; m < 16; m <<= 1) s += __shfl_xor(s, m, 64);
            if (cl == 0) norml[wv][mi * 16 + g * 4 + r] = s;
        }
    }
    __syncthreads();
    #pragma unroll
    for (int mi = 0; mi < 2; ++mi) {
        #pragma unroll
        for (int r = 0; r < 4; ++r) {
            const int rl = mi * 16 + g * 4 + r;
            float tot = 0.f;
            #pragma unroll
            for (int w = 0; w < 8; ++w) tot += norml[w][rl];
            const float rn = tot > 0.f ? rsqrtf(tot) : 1.0f;
            const int row = m0 + rl;
            if (row < M) {
                #pragma unroll
                for (int ni = 0; ni < 2; ++ni)
                    Cf[(size_t)row * 256 + n0 + ni * 16 + cl] = keep[mi][ni][r] * rn;
            }
        }
    }
}

// ---- per-dst aggregation: one wave per dst; unroll-4 on edges
__global__ __launch_bounds__(256) void aggregate_kernel(
    const unsigned short* __restrict__ nft, const float* __restrict__ h_dst,
    const float* __restrict__ weights, const int* __restrict__ src_idx,
    const int* __restrict__ edge_list, const int* __restrict__ offsets,
    unsigned short* __restrict__ xb)
{
    int d = blockIdx.x * 4 + (threadIdx.x >> 6);
    if (d >= N_DST) return;
    int lane = threadIdx.x & 63;
    int p0 = offsets[d], p1 = offsets[d + 1];
    float a0 = 0.f, a1 = 0.f, a2 = 0.f, a3 = 0.f, wsum = 0.f;
    int p = p0;
    for (; p + 3 < p1; p += 4) {
        int e0 = edge_list[p], e1 = edge_list[p + 1], e2 = edge_list[p + 2], e3 = edge_list[p + 3];
        float w0 = weights[e0], w1 = weights[e1], w2 = weights[e2], w3 = weights[e3];
        int s0 = src_idx[e0], s1 = src_idx[e1], s2 = src_idx[e2], s3 = src_idx[e3];
        uint2 v0 = *reinterpret_cast<const uint2*>(nft + (size_t)s0 * 256 + lane * 4);
        uint2 v1 = *reinterpret_cast<const uint2*>(nft + (size_t)s1 * 256 + lane * 4);
        uint2 v2 = *reinterpret_cast<const uint2*>(nft + (size_t)s2 * 256 + lane * 4);
        uint2 v3 = *reinterpret_cast<const uint2*>(nft + (size_t)s3 * 256 + lane * 4);
        wsum += (w0 + w1) + (w2 + w3);
        a0 += w0 * bf2f(v0.x & 0xffffu) + w1 * bf2f(v1.x & 0xffffu)
            + w2 * bf2f(v2.x & 0xffffu) + w3 * bf2f(v3.x & 0xffffu);
        a1 += w0 * bf2f(v0.x >> 16)     + w1 * bf2f(v1.x >> 16)
            + w2 * bf2f(v2.x >> 16)     + w3 * bf2f(v3.x >> 16);
        a2 += w0 * bf2f(v0.y & 0xffffu) + w1 * bf2f(v1.y & 0xffffu)
            + w2 * bf2f(v2.y & 0xffffu) + w3 * bf2f(v3.y & 0xffffu);
        a3 += w0 * bf2f(v0.y >> 16)     + w1 * bf2f(v1.y >> 16)
            + w2 * bf2f(v2.y >> 16)     + w3 * bf2f(v3.y >> 16);
    }
    for (; p < p1; ++p) {
        int e = edge_list[p];
        float w = weights[e];
        int s = src_idx[e];
        wsum += w;
        uint2 v = *reinterpret_cast<const uint2*>(nft + (size_t)s * 256 + lane * 4);
        a0 += w * bf2f(v.x & 0xffffu);
        a1 += w * bf2f(v.x >> 16);
        a2 += w * bf2f(v.y & 0xffffu);
        a3 += w * bf2f(v.y >> 16);
    }
    float inv = 1.0f / fmaxf(wsum, 1.0f);
    uint2 pk;
    pk.x = (unsigned)f2bf(a0 * inv) | ((unsigned)f2bf(a1 * inv) << 16);
    pk.y = (unsigned)f2bf(a2 * inv) | ((unsigned)f2bf(a3 * inv) << 16);
    *reinterpret_cast<uint2*>(xb + (size_t)d * 512 + lane * 4) = pk;
    float4 h = *reinterpret_cast<const float4*>(h_dst + (size_t)d * 256 + lane * 4);
    uint2 q;
    q.x = (unsigned)f2bf(h.x) | ((unsigned)f2bf(h.y) << 16);
    q.y = (unsigned)f2bf(h.z) | ((unsigned)f2bf(h.w) << 16);
    *reinterpret_cast<uint2*>(xb + (size_t)d * 512 + 256 + lane * 4) = q;
}

extern "C" void kernel_launch(void* const* d_in, const int* in_sizes, int n_in,
                              void* d_out, int out_size, void* d_ws, size_t ws_size,
                              hipStream_t stream) {
    const float* h_src   = (const float*)d_in[0];
    const float* h_dst   = (const float*)d_in[1];
    const float* weights = (const float*)d_in[2];
    const float* Q_w     = (const float*)d_in[3];
    const float* Q_b     = (const float*)d_in[4];
    const float* W_w     = (const float*)d_in[5];
    const float* W_b     = (const float*)d_in[6];
    const int* src_idx   = (const int*)d_in[7];
    const int* dst_idx   = (const int*)d_in[8];
    float* out = (float*)d_out;

    char* ws = (char*)d_ws;
    unsigned short* nft = (unsigned short*)(ws);               // 51,200,000
    unsigned short* xb  = (unsigned short*)(ws + 51200000);    // 25,600,000
    unsigned short* Qt  = (unsigned short*)(ws + 76800000);    // 131,072
    unsigned short* Wt  = (unsigned short*)(ws + 76931072);    // 262,144
    int* counts    = (int*)(ws + 77193216);                    // 100,000
    int* offsets   = (int*)(ws + 77293216);                    // 100,004
    int* edge_list = (int*)(ws + 77393220);                    // 1,200,000 (~78.6 MB)

    hipMemsetAsync(counts, 0, N_DST * sizeof(int), stream);

    cast_weights<<<768, 256, 0, stream>>>(Q_w, W_w, Qt, Wt);
    hist_kernel<<<(N_EDGE + 255) / 256, 256, 0, stream>>>(dst_idx, counts);
    scan_kernel<<<1, 1024, 0, stream>>>(counts, offsets, N_DST);
    scatter_kernel<<<(N_EDGE + 255) / 256, 256, 0, stream>>>(dst_idx, offsets, counts, edge_list);

    // 25000 waves (3125 row-tiles x 8 col-panels), 4 waves/block
    gemm1_stream<<<6250, 256, 0, stream>>>(h_src, Qt, Q_b, nft);

    aggregate_kernel<<<N_DST / 4, 256, 0, stream>>>(
        nft, h_dst, weights, src_idx, edge_list, offsets, xb);

    // 782 blocks x 8 waves: one 32-row tile per block, 8 col panels
    gemm2_stream<<<782, 512, 0, stream>>>(xb, Wt, W_b, out, N_DST);

    (void)in_sizes; (void)n_in; (void)out_size; (void)ws_size;
}

// Round 10
// 225.999 us; speedup vs baseline: 1.3630x; 1.3630x over previous
//
#include <hip/hip_runtime.h>
#include <hip/hip_bf16.h>
#include <cstdint>

#define N_SRC 100000
#define N_DST 25000
#define N_EDGE 300000
// D_IN = D_HID = D_OUT = 256, concat K = 512

typedef float f32x4 __attribute__((ext_vector_type(4)));
typedef __bf16 bf16x8 __attribute__((ext_vector_type(8)));

typedef const __attribute__((address_space(1))) void gv_t;
typedef __attribute__((address_space(3))) void lv_t;

__device__ __forceinline__ unsigned short f2bf(float f) {
    union { float f; unsigned int u; } v; v.f = f;
    unsigned int u = v.u;
    u += 0x7FFFu + ((u >> 16) & 1u);   // RNE; inputs finite
    return (unsigned short)(u >> 16);
}
__device__ __forceinline__ float bf2f(unsigned int bits16) {
    union { unsigned int u; float f; } v; v.u = bits16 << 16;
    return v.f;
}

// ---- cast + transpose weights: Qt[n][k] = bf16(Q_w[k][n]), Wt[n][k] = bf16(W_w[k][n])
__global__ void cast_weights(const float* __restrict__ Qw, const float* __restrict__ Ww,
                             unsigned short* __restrict__ Qt, unsigned short* __restrict__ Wt) {
    int i = blockIdx.x * blockDim.x + threadIdx.x;
    if (i < 256 * 256) {
        int n = i >> 8, k = i & 255;
        Qt[n * 256 + k] = f2bf(Qw[k * 256 + n]);
    } else if (i < 256 * 256 + 512 * 256) {
        int j = i - 256 * 256;
        int n = j >> 9, k = j & 511;
        Wt[n * 512 + k] = f2bf(Ww[k * 256 + n]);
    }
}

// ---- CSR build
__global__ void hist_kernel(const int* __restrict__ dst_idx, int* __restrict__ counts) {
    int i = blockIdx.x * blockDim.x + threadIdx.x;
    if (i < N_EDGE) atomicAdd(&counts[dst_idx[i]], 1);
}

__global__ __launch_bounds__(1024) void scan_kernel(const int* __restrict__ counts,
                                                    int* __restrict__ offsets, int n) {
    __shared__ int wsum[16];
    const int t = threadIdx.x;
    const int wid = t >> 6, lane = t & 63;
    int carry = 0;
    if (t == 0) offsets[0] = 0;
    for (int base = 0; base < n; base += 1024) {
        int x = (base + t < n) ? counts[base + t] : 0;
        #pragma unroll
        for (int off = 1; off < 64; off <<= 1) {
            int y = __shfl_up(x, off, 64);
            if (lane >= off) x += y;
        }
        if (lane == 63) wsum[wid] = x;
        __syncthreads();
        if (t < 16) {
            int w = wsum[t];
            #pragma unroll
            for (int off = 1; off < 16; off <<= 1) {
                int y = __shfl_up(w, off, 64);
                if (t >= off) w += y;
            }
            wsum[t] = w;
        }
        __syncthreads();
        int pre = (wid > 0) ? wsum[wid - 1] : 0;
        int incl = carry + pre + x;
        if (base + t < n) offsets[base + t + 1] = incl;
        carry += wsum[15];
        __syncthreads();
    }
}

__global__ void scatter_kernel(const int* __restrict__ dst_idx, const int* __restrict__ offsets,
                               int* __restrict__ counts, int* __restrict__ edge_list) {
    int i = blockIdx.x * blockDim.x + threadIdx.x;
    if (i < N_EDGE) {
        int d = dst_idx[i];
        int pos = offsets[d] + (atomicSub(&counts[d], 1) - 1);
        edge_list[pos] = i;
    }
}

// ---- GEMM1 v2: nft = relu(h_src @ Qt^T + Qb), bf16 out.
// Block 64 rows x 256 cols, 4 waves (one 64-col panel each).
// A: staged ONCE (whole K=256) into 32KB LDS as bf16, XOR-swizzled 16B chunks.
// B: wave's full 64x256 panel in registers (32 uint4), loaded ONCE from L2.
// One barrier; compute loop touches only LDS + regs. waves_per_eu(1,2) gives
// the allocator a 256-VGPR budget so nothing spills or gets sunk.
__global__ __launch_bounds__(256) __attribute__((amdgpu_waves_per_eu(1, 2)))
void gemm1_v2(const float* __restrict__ Af, const unsigned short* __restrict__ Bt,
              const float* __restrict__ bias, unsigned short* __restrict__ Cb)
{
    __shared__ __align__(16) unsigned char As[32768];   // 64 rows x 512B
    const int tid = threadIdx.x;
    const int wv = tid >> 6, lane = tid & 63, g = lane >> 4, cl = lane & 15;
    const int m0 = blockIdx.x * 64;
    const int n0 = wv * 64;

    // B panel -> regs; latency hidden under A staging + barrier
    uint4 Br[4][8];
    #pragma unroll
    for (int ni = 0; ni < 4; ++ni)
        #pragma unroll
        for (int kf = 0; kf < 8; ++kf)
            Br[ni][kf] = *reinterpret_cast<const uint4*>(
                Bt + (size_t)(n0 + ni * 16 + cl) * 256 + kf * 32 + g * 8);

    // stage A: thread = (row = tid>>2, quarter q = tid&3); 8 chunks of 8 f32 -> 8 bf16
    {
        const int row = tid >> 2, q = tid & 3;
        const int grow = min(m0 + row, N_SRC - 1);
        const float* gp = Af + (size_t)grow * 256 + q * 64;
        #pragma unroll
        for (int j = 0; j < 8; ++j) {
            const float4 lo = *reinterpret_cast<const float4*>(gp + j * 8);
            const float4 hi = *reinterpret_cast<const float4*>(gp + j * 8 + 4);
            uint4 pk;
            pk.x = (unsigned)f2bf(lo.x) | ((unsigned)f2bf(lo.y) << 16);
            pk.y = (unsigned)f2bf(lo.z) | ((unsigned)f2bf(lo.w) << 16);
            pk.z = (unsigned)f2bf(hi.x) | ((unsigned)f2bf(hi.y) << 16);
            pk.w = (unsigned)f2bf(hi.z) | ((unsigned)f2bf(hi.w) << 16);
            const int c = q * 8 + j;
            *reinterpret_cast<uint4*>(&As[row * 512 + ((c ^ (row & 7)) << 4)]) = pk;
        }
    }
    __syncthreads();

    f32x4 acc[4][4] = {};
    #pragma unroll
    for (int kf = 0; kf < 8; ++kf) {
        bf16x8 af[4];
        #pragma unroll
        for (int mi = 0; mi < 4; ++mi) {
            const int row = mi * 16 + cl;
            af[mi] = *reinterpret_cast<const bf16x8*>(
                &As[row * 512 + (((kf * 4 + g) ^ (cl & 7)) << 4)]);
        }
        #pragma unroll
        for (int mi = 0; mi < 4; ++mi)
            #pragma unroll
            for (int ni = 0; ni < 4; ++ni)
                acc[mi][ni] = __builtin_amdgcn_mfma_f32_16x16x32_bf16(
                    af[mi], __builtin_bit_cast(bf16x8, Br[ni][kf]), acc[mi][ni], 0, 0, 0);
    }

    float bcol[4];
    #pragma unroll
    for (int ni = 0; ni < 4; ++ni) bcol[ni] = bias[n0 + ni * 16 + cl];
    #pragma unroll
    for (int mi = 0; mi < 4; ++mi) {
        const int rowb = m0 + mi * 16 + g * 4;
        #pragma unroll
        for (int ni = 0; ni < 4; ++ni) {
            const int col = n0 + ni * 16 + cl;
            #pragma unroll
            for (int r = 0; r < 4; ++r) {
                const int row = rowb + r;
                if (row < N_SRC) {
                    float v = fmaxf(acc[mi][ni][r] + bcol[ni], 0.f);
                    Cb[(size_t)row * 256 + col] = f2bf(v);
                }
            }
        }
    }
}

// ---- GEMM2 v2: out = rownorm(relu(xb @ Wt^T + Wb)), f32 out.
// Same structure, K=512: A (bf16) staged whole-K into 64KB LDS via
// global_load_lds (pre-swizzled source, linear dest — rule #21);
// B panel in regs in two half-K phases (32 uint4 each). Row-norm epilogue
// exchanges per-panel ssq through norml aliased onto As.
__global__ __launch_bounds__(256) __attribute__((amdgpu_waves_per_eu(1, 2)))
void gemm2_v2(const unsigned short* __restrict__ Ab, const unsigned short* __restrict__ Bt,
              const float* __restrict__ bias, float* __restrict__ Cf, int M)
{
    __shared__ __align__(16) unsigned char As[65536];   // 64 rows x 1KB
    const int tid = threadIdx.x;
    const int wv = tid >> 6, lane = tid & 63, g = lane >> 4, cl = lane & 15;
    const int m0 = blockIdx.x * 64;
    const int n0 = wv * 64;

    uint4 Br[4][8];
    auto loadB = [&](int p) {
        #pragma unroll
        for (int ni = 0; ni < 4; ++ni)
            #pragma unroll
            for (int kf = 0; kf < 8; ++kf)
                Br[ni][kf] = *reinterpret_cast<const uint4*>(
                    Bt + (size_t)(n0 + ni * 16 + cl) * 512 + (p * 8 + kf) * 32 + g * 8);
    };
    loadB(0);

    // stage A whole-K via global_load_lds: wave wv stages rows wv*16..+15,
    // one 1KB row per instr; source chunk pre-XOR'd so reads can swizzle.
    #pragma unroll
    for (int j = 0; j < 16; ++j) {
        const int row = wv * 16 + j;
        const int grow = min(m0 + row, M - 1);
        const unsigned short* gp = Ab + (size_t)grow * 512 + ((lane ^ (row & 7)) << 3);
        __builtin_amdgcn_global_load_lds((gv_t*)gp, (lv_t*)&As[row * 1024], 16, 0, 0);
    }
    __syncthreads();

    f32x4 acc[4][4] = {};
    #pragma unroll
    for (int kf = 0; kf < 8; ++kf) {
        bf16x8 af[4];
        #pragma unroll
        for (int mi = 0; mi < 4; ++mi) {
            const int row = mi * 16 + cl;
            af[mi] = *reinterpret_cast<const bf16x8*>(
                &As[row * 1024 + (((kf * 4 + g) ^ (cl & 7)) << 4)]);
        }
        #pragma unroll
        for (int mi = 0; mi < 4; ++mi)
            #pragma unroll
            for (int ni = 0; ni < 4; ++ni)
                acc[mi][ni] = __builtin_amdgcn_mfma_f32_16x16x32_bf16(
                    af[mi], __builtin_bit_cast(bf16x8, Br[ni][kf]), acc[mi][ni], 0, 0, 0);
    }
    loadB(1);
    #pragma unroll
    for (int kf = 8; kf < 16; ++kf) {
        bf16x8 af[4];
        #pragma unroll
        for (int mi = 0; mi < 4; ++mi) {
            const int row = mi * 16 + cl;
            af[mi] = *reinterpret_cast<const bf16x8*>(
                &As[row * 1024 + (((kf * 4 + g) ^ (cl & 7)) << 4)]);
        }
        #pragma unroll
        for (int mi = 0; mi < 4; ++mi)
            #pragma unroll
            for (int ni = 0; ni < 4; ++ni)
                acc[mi][ni] = __builtin_amdgcn_mfma_f32_16x16x32_bf16(
                    af[mi], __builtin_bit_cast(bf16x8, Br[ni][kf - 8]), acc[mi][ni], 0, 0, 0);
    }

    float bcol[4];
    #pragma unroll
    for (int ni = 0; ni < 4; ++ni) bcol[ni] = bias[n0 + ni * 16 + cl];

    float ssq[4][4];
    #pragma unroll
    for (int mi = 0; mi < 4; ++mi) {
        #pragma unroll
        for (int r = 0; r < 4; ++r) {
            float s = 0.f;
            #pragma unroll
            for (int ni = 0; ni < 4; ++ni) {
                float v = fmaxf(acc[mi][ni][r] + bcol[ni], 0.f);
                acc[mi][ni][r] = v;
                s += v * v;
            }
            #pragma unroll
            for (int m = 1; m < 16; m <<= 1) s += __shfl_xor(s, m, 64);
            ssq[mi][r] = s;
        }
    }
    __syncthreads();                       // all A reads done; reuse As for norml
    float* norml = reinterpret_cast<float*>(As);   // [4][64]
    if (cl == 0) {
        #pragma unroll
        for (int mi = 0; mi < 4; ++mi)
            #pragma unroll
            for (int r = 0; r < 4; ++r)
                norml[wv * 64 + mi * 16 + g * 4 + r] = ssq[mi][r];
    }
    __syncthreads();
    #pragma unroll
    for (int mi = 0; mi < 4; ++mi) {
        #pragma unroll
        for (int r = 0; r < 4; ++r) {
            const int rl = mi * 16 + g * 4 + r;
            const float tot = norml[rl] + norml[64 + rl] + norml[128 + rl] + norml[192 + rl];
            const float rn = tot > 0.f ? rsqrtf(tot) : 1.0f;
            const int row = m0 + rl;
            if (row < M) {
                #pragma unroll
                for (int ni = 0; ni < 4; ++ni)
                    Cf[(size_t)row * 256 + n0 + ni * 16 + cl] = acc[mi][ni][r] * rn;
            }
        }
    }
}

// ---- per-dst aggregation: one wave per dst; unroll-4 on edges
__global__ __launch_bounds__(256) void aggregate_kernel(
    const unsigned short* __restrict__ nft, const float* __restrict__ h_dst,
    const float* __restrict__ weights, const int* __restrict__ src_idx,
    const int* __restrict__ edge_list, const int* __restrict__ offsets,
    unsigned short* __restrict__ xb)
{
    int d = blockIdx.x * 4 + (threadIdx.x >> 6);
    if (d >= N_DST) return;
    int lane = threadIdx.x & 63;
    int p0 = offsets[d], p1 = offsets[d + 1];
    float a0 = 0.f, a1 = 0.f, a2 = 0.f, a3 = 0.f, wsum = 0.f;
    int p = p0;
    for (; p + 3 < p1; p += 4) {
        int e0 = edge_list[p], e1 = edge_list[p + 1], e2 = edge_list[p + 2], e3 = edge_list[p + 3];
        float w0 = weights[e0], w1 = weights[e1], w2 = weights[e2], w3 = weights[e3];
        int s0 = src_idx[e0], s1 = src_idx[e1], s2 = src_idx[e2], s3 = src_idx[e3];
        uint2 v0 = *reinterpret_cast<const uint2*>(nft + (size_t)s0 * 256 + lane * 4);
        uint2 v1 = *reinterpret_cast<const uint2*>(nft + (size_t)s1 * 256 + lane * 4);
        uint2 v2 = *reinterpret_cast<const uint2*>(nft + (size_t)s2 * 256 + lane * 4);
        uint2 v3 = *reinterpret_cast<const uint2*>(nft + (size_t)s3 * 256 + lane * 4);
        wsum += (w0 + w1) + (w2 + w3);
        a0 += w0 * bf2f(v0.x & 0xffffu) + w1 * bf2f(v1.x & 0xffffu)
            + w2 * bf2f(v2.x & 0xffffu) + w3 * bf2f(v3.x & 0xffffu);
        a1 += w0 * bf2f(v0.x >> 16)     + w1 * bf2f(v1.x >> 16)
            + w2 * bf2f(v2.x >> 16)     + w3 * bf2f(v3.x >> 16);
        a2 += w0 * bf2f(v0.y & 0xffffu) + w1 * bf2f(v1.y & 0xffffu)
            + w2 * bf2f(v2.y & 0xffffu) + w3 * bf2f(v3.y & 0xffffu);
        a3 += w0 * bf2f(v0.y >> 16)     + w1 * bf2f(v1.y >> 16)
            + w2 * bf2f(v2.y >> 16)     + w3 * bf2f(v3.y >> 16);
    }
    for (; p < p1; ++p) {
        int e = edge_list[p];
        float w = weights[e];
        int s = src_idx[e];
        wsum += w;
        uint2 v = *reinterpret_cast<const uint2*>(nft + (size_t)s * 256 + lane * 4);
        a0 += w * bf2f(v.x & 0xffffu);
        a1 += w * bf2f(v.x >> 16);
        a2 += w * bf2f(v.y & 0xffffu);
        a3 += w * bf2f(v.y >> 16);
    }
    float inv = 1.0f / fmaxf(wsum, 1.0f);
    uint2 pk;
    pk.x = (unsigned)f2bf(a0 * inv) | ((unsigned)f2bf(a1 * inv) << 16);
    pk.y = (unsigned)f2bf(a2 * inv) | ((unsigned)f2bf(a3 * inv) << 16);
    *reinterpret_cast<uint2*>(xb + (size_t)d * 512 + lane * 4) = pk;
    float4 h = *reinterpret_cast<const float4*>(h_dst + (size_t)d * 256 + lane * 4);
    uint2 q;
    q.x = (unsigned)f2bf(h.x) | ((unsigned)f2bf(h.y) << 16);
    q.y = (unsigned)f2bf(h.z) | ((unsigned)f2bf(h.w) << 16);
    *reinterpret_cast<uint2*>(xb + (size_t)d * 512 + 256 + lane * 4) = q;
}

extern "C" void kernel_launch(void* const* d_in, const int* in_sizes, int n_in,
                              void* d_out, int out_size, void* d_ws, size_t ws_size,
                              hipStream_t stream) {
    const float* h_src   = (const float*)d_in[0];
    const float* h_dst   = (const float*)d_in[1];
    const float* weights = (const float*)d_in[2];
    const float* Q_w     = (const float*)d_in[3];
    const float* Q_b     = (const float*)d_in[4];
    const float* W_w     = (const float*)d_in[5];
    const float* W_b     = (const float*)d_in[6];
    const int* src_idx   = (const int*)d_in[7];
    const int* dst_idx   = (const int*)d_in[8];
    float* out = (float*)d_out;

    char* ws = (char*)d_ws;
    unsigned short* nft = (unsigned short*)(ws);               // 51,200,000
    unsigned short* xb  = (unsigned short*)(ws + 51200000);    // 25,600,000
    unsigned short* Qt  = (unsigned short*)(ws + 76800000);    // 131,072
    unsigned short* Wt  = (unsigned short*)(ws + 76931072);    // 262,144
    int* counts    = (int*)(ws + 77193216);                    // 100,000
    int* offsets   = (int*)(ws + 77293216);                    // 100,004
    int* edge_list = (int*)(ws + 77393220);                    // 1,200,000 (~78.6 MB)

    hipMemsetAsync(counts, 0, N_DST * sizeof(int), stream);

    cast_weights<<<768, 256, 0, stream>>>(Q_w, W_w, Qt, Wt);
    hist_kernel<<<(N_EDGE + 255) / 256, 256, 0, stream>>>(dst_idx, counts);
    scan_kernel<<<1, 1024, 0, stream>>>(counts, offsets, N_DST);
    scatter_kernel<<<(N_EDGE + 255) / 256, 256, 0, stream>>>(dst_idx, offsets, counts, edge_list);

    gemm1_v2<<<(N_SRC + 63) / 64, 256, 0, stream>>>(h_src, Qt, Q_b, nft);

    aggregate_kernel<<<N_DST / 4, 256, 0, stream>>>(
        nft, h_dst, weights, src_idx, edge_list, offsets, xb);

    gemm2_v2<<<(N_DST + 63) / 64, 256, 0, stream>>>(xb, Wt, W_b, out, N_DST);

    (void)in_sizes; (void)n_in; (void)out_size; (void)ws_size;
}